// Round 1
// baseline (1488.576 us; speedup 1.0000x reference)
//
#include <hip/hip_runtime.h>
#include <math.h>

// WindAdvectionBlock: B=8, C=256, H=W=128, mid=64
// Pipeline: compress(1x1) -> off1(3x3)+gelu -> off2(3x3) -> deform_conv(3x3)
//           -> expand(1x1) -> GroupNorm(4) -> gelu -> +features
// All intermediates NHWC in ws. GN stats computed analytically from
// ybar = sum_p y, Y2 = sum_p y y^T (z is affine in y), so z is never stored.

#define BB 8
#define CC 256
#define HH 128
#define WW 128
#define HW 16384
#define MID 64

__device__ __forceinline__ float gelu_f(float v){
  return 0.5f*v*(1.0f + erff(v*0.7071067811865476f));
}

// ---- prep: transpose deform_w [64][64][9] -> wt[9][64][64]; expand_w [256][64] -> ewt[64][256]
__global__ void k_prep(const float* __restrict__ dw, const float* __restrict__ ew,
                       float* __restrict__ wt, float* __restrict__ ewt){
  int i = blockIdx.x*256 + threadIdx.x;
  if (i < 9*64*64){
    int k = i >> 12;
    int r = i & 4095;
    int o = r >> 6, c = r & 63;
    wt[i] = dw[(o*64+c)*9 + k];
  }
  int j = i - 9*64*64;
  if (j >= 0 && j < 64*256){
    int m = j >> 8, c = j & 255;
    ewt[j] = ew[c*64 + m];
  }
}

// ---- compress 1x1: feat NCHW -> x NHWC [b][p][64]
__global__ __launch_bounds__(256) void k_compress(const float* __restrict__ feat,
    const float* __restrict__ cw, const float* __restrict__ cb, float* __restrict__ xo){
  __shared__ float wl[256*64];           // wl[c*64+m] = cw[m*256+c]  (64KB)
  int t = threadIdx.x;
  for (int i=t;i<256*64;i+=256){ int c=i>>6, m=i&63; wl[i]=cw[m*256+c]; }
  __syncthreads();
  int b = blockIdx.y;
  int p = blockIdx.x*256 + t;
  const float* fp = feat + (size_t)b*CC*HW + p;
  float acc[64];
  #pragma unroll
  for (int m=0;m<64;m++) acc[m]=cb[m];
  #pragma unroll 2
  for (int c=0;c<256;c++){
    float f = fp[(size_t)c*HW];
    const float* w = &wl[c*64];
    #pragma unroll
    for (int m=0;m<64;m+=4){
      float4 w4 = *(const float4*)(w+m);
      acc[m]+=f*w4.x; acc[m+1]+=f*w4.y; acc[m+2]+=f*w4.z; acc[m+3]+=f*w4.w;
    }
  }
  float* xp = xo + ((size_t)b*HW + p)*64;
  #pragma unroll
  for (int m=0;m<64;m+=4) *(float4*)(xp+m)=make_float4(acc[m],acc[m+1],acc[m+2],acc[m+3]);
}

// ---- off1: wind [b][2][H][W] -> h NHWC [b][p][32], conv3x3 pad1 + gelu
__global__ __launch_bounds__(256) void k_off1(const float* __restrict__ wind,
    const float* __restrict__ w1, const float* __restrict__ b1, float* __restrict__ ho){
  __shared__ float wl[576];              // [o][c][k] = [32][2][9]
  int t=threadIdx.x;
  for (int i=t;i<576;i+=256) wl[i]=w1[i];
  __syncthreads();
  int b=blockIdx.y; int p=blockIdx.x*256+t;
  int y=p>>7, x=p&127;
  float tap[18];
  #pragma unroll
  for (int c=0;c<2;c++){
    #pragma unroll
    for (int ki=0;ki<3;ki++){
      #pragma unroll
      for (int kj=0;kj<3;kj++){
        int yy=y+ki-1, xx=x+kj-1;
        float v=0.f;
        if ((unsigned)yy<128u && (unsigned)xx<128u)
          v = wind[((size_t)b*2+c)*HW + (yy<<7)+xx];
        tap[c*9+ki*3+kj]=v;
      }
    }
  }
  float outv[32];
  #pragma unroll
  for (int o=0;o<32;o++){
    float a=b1[o];
    #pragma unroll
    for (int i=0;i<18;i++) a += tap[i]*wl[o*18+i];
    outv[o]=gelu_f(a);
  }
  float* hp = ho + ((size_t)b*HW+p)*32;
  #pragma unroll
  for (int o=0;o<32;o+=4) *(float4*)(hp+o)=make_float4(outv[o],outv[o+1],outv[o+2],outv[o+3]);
}

// ---- off2: h NHWC [b][p][32] -> offsets NHWC [b][p][18], conv3x3 pad1
__global__ __launch_bounds__(256) void k_off2(const float* __restrict__ h,
    const float* __restrict__ w2, const float* __restrict__ b2, float* __restrict__ oo){
  __shared__ float wl[9*18*32];          // wl[(k*18+o)*32+c] (20.7KB)
  int t=threadIdx.x;
  for (int i=t;i<5184;i+=256){
    int k=i/576; int r=i-k*576; int o=r>>5; int c=r&31;
    wl[i] = w2[(o*32+c)*9+k];
  }
  __syncthreads();
  int b=blockIdx.y; int p=blockIdx.x*256+t;
  int y=p>>7, x=p&127;
  float acc[18];
  #pragma unroll
  for (int o=0;o<18;o++) acc[o]=b2[o];
  for (int ki=0;ki<3;ki++){
    for (int kj=0;kj<3;kj++){
      int k = ki*3+kj;
      int yy=y+ki-1, xx=x+kj-1;
      float4 hv[8];
      if ((unsigned)yy<128u && (unsigned)xx<128u){
        const float* hp = h + ((size_t)b*HW + (yy<<7)+xx)*32;
        #pragma unroll
        for (int q=0;q<8;q++) hv[q]=*(const float4*)(hp+q*4);
      } else {
        #pragma unroll
        for (int q=0;q<8;q++) hv[q]=make_float4(0.f,0.f,0.f,0.f);
      }
      const float* wk = &wl[k*576];
      #pragma unroll
      for (int o=0;o<18;o++){
        float a=acc[o];
        #pragma unroll
        for (int q=0;q<8;q++){
          float4 w4 = *(const float4*)(wk + o*32 + q*4);
          a += hv[q].x*w4.x + hv[q].y*w4.y + hv[q].z*w4.z + hv[q].w*w4.w;
        }
        acc[o]=a;
      }
    }
  }
  float* op = oo + ((size_t)b*HW+p)*18;
  #pragma unroll
  for (int o=0;o<18;o+=2) *(float2*)(op+o)=make_float2(acc[o],acc[o+1]);
}

// ---- deform conv: x NHWC, offsets NHWC, wt[9][64][64] -> y NHWC [b][p][64]
__global__ __launch_bounds__(256) void k_deform(const float* __restrict__ x,
    const float* __restrict__ off, const float* __restrict__ wt,
    const float* __restrict__ db, float* __restrict__ yo){
  __shared__ float WK[4096];             // 16KB, W[o][c] for current k
  int t=threadIdx.x;
  int b=blockIdx.y; int p=blockIdx.x*256+t;
  int yy=p>>7, xx=p&127;
  const float* offp = off + ((size_t)b*HW+p)*18;
  const float* xb = x + (size_t)b*HW*64;
  float acc[64];
  #pragma unroll
  for (int o=0;o<64;o++) acc[o]=0.f;
  for (int ki=0;ki<3;ki++){
    for (int kj=0;kj<3;kj++){
      int k = ki*3+kj;
      __syncthreads();
      const float* wtk = wt + k*4096;
      for (int i=t*4;i<4096;i+=1024) *(float4*)&WK[i] = *(const float4*)(wtk+i);
      __syncthreads();
      float2 dd = *(const float2*)(offp + 2*k);
      float py = dd.x + (float)(yy + ki - 1);
      float px = dd.y + (float)(xx + kj - 1);
      float y0f = floorf(py), x0f = floorf(px);
      float fy = py - y0f, fx = px - x0f;
      int y0 = (int)y0f, x0 = (int)x0f;
      float w00=(1.f-fy)*(1.f-fx), w01=(1.f-fy)*fx, w10=fy*(1.f-fx), w11=fy*fx;
      bool v0 = ((unsigned)y0 < 128u), v1 = ((unsigned)(y0+1) < 128u);
      bool u0 = ((unsigned)x0 < 128u), u1 = ((unsigned)(x0+1) < 128u);
      bool b00=v0&&u0, b01=v0&&u1, b10=v1&&u0, b11=v1&&u1;
      long base = (long)y0*8192 + (long)x0*64;
      const float4 z4 = make_float4(0.f,0.f,0.f,0.f);
      for (int c4=0;c4<64;c4+=4){
        float4 v00 = b00 ? *(const float4*)(xb+base+c4)        : z4;
        float4 v01 = b01 ? *(const float4*)(xb+base+64+c4)     : z4;
        float4 v10 = b10 ? *(const float4*)(xb+base+8192+c4)   : z4;
        float4 v11 = b11 ? *(const float4*)(xb+base+8256+c4)   : z4;
        float4 s;
        s.x = v00.x*w00 + v01.x*w01 + v10.x*w10 + v11.x*w11;
        s.y = v00.y*w00 + v01.y*w01 + v10.y*w10 + v11.y*w11;
        s.z = v00.z*w00 + v01.z*w01 + v10.z*w10 + v11.z*w11;
        s.w = v00.w*w00 + v01.w*w01 + v10.w*w10 + v11.w*w11;
        #pragma unroll
        for (int o=0;o<64;o++){
          float4 w4 = *(const float4*)&WK[(o<<6)+c4];
          acc[o] += s.x*w4.x + s.y*w4.y + s.z*w4.z + s.w*w4.w;
        }
      }
    }
  }
  float* yp = yo + ((size_t)b*HW+p)*64;
  #pragma unroll
  for (int o=0;o<64;o+=4)
    *(float4*)(yp+o) = make_float4(acc[o]+db[o], acc[o+1]+db[o+1], acc[o+2]+db[o+2], acc[o+3]+db[o+3]);
}

// ---- stats: ybar[b][64] = sum_p y, Y2[b][64][64] = sum_p y y^T (atomic partials)
__global__ __launch_bounds__(256) void k_stats(const float* __restrict__ y,
    float* __restrict__ Y2, float* __restrict__ ybar){
  __shared__ float yt[128*64];           // 32KB
  int t=threadIdx.x; int b=blockIdx.y;
  const float* yp = y + ((size_t)b*HW + blockIdx.x*128)*64;
  for (int i=t*4;i<8192;i+=1024) *(float4*)&yt[i]=*(const float4*)(yp+i);
  __syncthreads();
  int i = t&63, jb = t>>6;
  float acc[16];
  #pragma unroll
  for (int j=0;j<16;j++) acc[j]=0.f;
  for (int p=0;p<128;p++){
    float yi = yt[(p<<6)+i];
    const float* yj = &yt[(p<<6)+(jb<<4)];
    #pragma unroll
    for (int q=0;q<4;q++){
      float4 v=*(const float4*)(yj+q*4);
      acc[q*4]+=yi*v.x; acc[q*4+1]+=yi*v.y; acc[q*4+2]+=yi*v.z; acc[q*4+3]+=yi*v.w;
    }
  }
  float* Y2b = Y2 + ((size_t)b<<12) + (i<<6) + (jb<<4);
  #pragma unroll
  for (int j=0;j<16;j++) atomicAdd(Y2b+j, acc[j]);
  if (t<64){
    float s=0.f;
    for (int p=0;p<128;p++) s+=yt[(p<<6)+t];
    atomicAdd(ybar+(b<<6)+t, s);
  }
}

// ---- analytic GN stats: per (b,g): mu, rstd of z = expand(y) over 64ch x HW
__global__ __launch_bounds__(256) void k_gn(const float* __restrict__ Y2,
    const float* __restrict__ ybar, const float* __restrict__ ew,
    const float* __restrict__ eb, float* __restrict__ stats){
  __shared__ float wsm[64*65];
  __shared__ float red[512];
  int t=threadIdx.x;
  int bg=blockIdx.x, b=bg>>2, g=bg&3;
  for (int i=t;i<4096;i+=256){
    int c=i>>6, m=i&63;
    wsm[c*65+m] = ew[(((size_t)g<<6)+c)*64 + m];
  }
  __syncthreads();
  int c = t&63, qm = t>>6;
  const float* wv = &wsm[c*65];
  const float* Y2b = Y2 + ((size_t)b<<12);
  const float* yb = ybar + (b<<6);
  float q=0.f, sbp=0.f;
  for (int m=qm*16; m<qm*16+16; m++){
    const float* row = Y2b + (m<<6);
    float ym=0.f;
    for (int n=0;n<64;n+=4){
      float4 r4=*(const float4*)(row+n);
      ym += r4.x*wv[n] + r4.y*wv[n+1] + r4.z*wv[n+2] + r4.w*wv[n+3];
    }
    q += ym*wv[m];
    sbp += wv[m]*yb[m];
  }
  float bias = eb[(g<<6)+c];
  float pz  = sbp + (qm==0 ? 16384.f*bias : 0.f);
  float pz2 = q + 2.f*bias*sbp + (qm==0 ? 16384.f*bias*bias : 0.f);
  red[t]=pz; red[256+t]=pz2;
  __syncthreads();
  for (int s=128;s>0;s>>=1){
    if (t<s){ red[t]+=red[t+s]; red[256+t]+=red[256+t+s]; }
    __syncthreads();
  }
  if (t==0){
    const float N=64.f*16384.f;
    float mu = red[0]/N;
    float var = red[256]/N - mu*mu;
    stats[bg*2]=mu; stats[bg*2+1]=rsqrtf(var+1e-5f);
  }
}

// ---- final: recompute z = expand(y), GN apply, gelu, + features -> out NCHW
__global__ __launch_bounds__(256) void k_final(const float* __restrict__ y,
    const float* __restrict__ ewt, const float* __restrict__ eb,
    const float* __restrict__ stats, const float* __restrict__ gamma,
    const float* __restrict__ beta, const float* __restrict__ feat,
    float* __restrict__ out){
  __shared__ float yt[128*65];           // y tile [px][m], pad 65 (33.3KB)
  __shared__ float wl[64*68];            // W^T block [m][c_local], pad 68 (17.4KB)
  int t=threadIdx.x; int b=blockIdx.y; int g=blockIdx.z;
  int p0 = blockIdx.x*128;
  const float* yp = y + ((size_t)b*HW+p0)*64;
  for (int i=t*4;i<8192;i+=1024){
    float4 v=*(const float4*)(yp+i);
    int l=i>>6, m=i&63;
    float* dst=&yt[l*65+m];
    dst[0]=v.x; dst[1]=v.y; dst[2]=v.z; dst[3]=v.w;
  }
  for (int i=t;i<4096;i+=256){
    int m=i>>6, cl=i&63;
    wl[m*68+cl] = ewt[(m<<8) + (g<<6) + cl];
  }
  __syncthreads();
  int l = t & 127, ch = (t>>7)<<5;       // c_local base: 0 or 32
  int p = p0 + l;
  int cg0 = (g<<6) + ch;
  float acc[32];
  #pragma unroll
  for (int j=0;j<32;j++) acc[j]=eb[cg0+j];
  for (int m=0;m<64;m++){
    float yv = yt[l*65+m];
    const float* wm = &wl[m*68+ch];
    #pragma unroll
    for (int q=0;q<8;q++){
      float4 w4=*(const float4*)(wm+q*4);
      acc[q*4]+=yv*w4.x; acc[q*4+1]+=yv*w4.y; acc[q*4+2]+=yv*w4.z; acc[q*4+3]+=yv*w4.w;
    }
  }
  float mu = stats[(((b<<2)+g)<<1)], rstd = stats[(((b<<2)+g)<<1)+1];
  #pragma unroll
  for (int j=0;j<32;j++){
    int cg = cg0 + j;
    float zn = (acc[j]-mu)*rstd;
    float val = zn*gamma[cg] + beta[cg];
    size_t idx = ((size_t)b*CC + cg)*HW + p;
    out[idx] = feat[idx] + gelu_f(val);
  }
}

extern "C" void kernel_launch(void* const* d_in, const int* in_sizes, int n_in,
                              void* d_out, int out_size, void* d_ws, size_t ws_size,
                              hipStream_t stream){
  const float* feat = (const float*)d_in[0];
  const float* wind = (const float*)d_in[1];
  const float* cw   = (const float*)d_in[2];
  const float* cb   = (const float*)d_in[3];
  const float* w1   = (const float*)d_in[4];
  const float* b1   = (const float*)d_in[5];
  const float* w2   = (const float*)d_in[6];
  const float* b2   = (const float*)d_in[7];
  const float* dw   = (const float*)d_in[8];
  const float* db   = (const float*)d_in[9];
  const float* ew   = (const float*)d_in[10];
  const float* ebias= (const float*)d_in[11];
  const float* gg   = (const float*)d_in[12];
  const float* gb   = (const float*)d_in[13];
  float* ws = (float*)d_ws;
  // ws layout (floats)
  float* x_nhwc   = ws;                    // 8*16384*64  = 8388608
  float* y_nhwc   = ws + 8388608;          // 8388608
  float* h_nhwc   = ws + 16777216;         // 8*16384*32 = 4194304
  float* off_nhwc = ws + 20971520;         // 8*16384*18 = 2359296
  float* wt       = ws + 23330816;         // 9*64*64 = 36864
  float* ewt      = ws + 23367680;         // 64*256  = 16384
  float* Y2       = ws + 23384064;         // 8*4096  = 32768
  float* ybar     = ws + 23416832;         // 8*64    = 512
  float* stats    = ws + 23417344;         // 8*4*2   = 64
  // zero atomic accumulators (Y2 + ybar contiguous)
  hipMemsetAsync(Y2, 0, (32768+512)*sizeof(float), stream);
  k_prep<<<208,256,0,stream>>>(dw, ew, wt, ewt);
  k_compress<<<dim3(64,8),256,0,stream>>>(feat, cw, cb, x_nhwc);
  k_off1<<<dim3(64,8),256,0,stream>>>(wind, w1, b1, h_nhwc);
  k_off2<<<dim3(64,8),256,0,stream>>>(h_nhwc, w2, b2, off_nhwc);
  k_deform<<<dim3(64,8),256,0,stream>>>(x_nhwc, off_nhwc, wt, db, y_nhwc);
  k_stats<<<dim3(128,8),256,0,stream>>>(y_nhwc, Y2, ybar);
  k_gn<<<32,256,0,stream>>>(Y2, ybar, ew, ebias, stats);
  k_final<<<dim3(128,8,4),256,0,stream>>>(y_nhwc, ewt, ebias, stats, gg, gb, feat, (float*)d_out);
}

// Round 2
// 1370.264 us; speedup vs baseline: 1.0863x; 1.0863x over previous
//
#include <hip/hip_runtime.h>
#include <math.h>

// WindAdvectionBlock: B=8, C=256, H=W=128, mid=64
// compress(1x1) -> off1(3x3)+gelu -> off2(3x3) -> deform_conv(3x3, MFMA bf16)
//   -> expand(1x1) -> GroupNorm(4) -> gelu -> +features
// Intermediates NHWC. GN stats computed analytically from ybar/Y2 (z affine in y).

#define BB 8
#define CC 256
#define HH 128
#define WW 128
#define HW 16384
#define MID 64

typedef __attribute__((ext_vector_type(8))) short bf16x8;
typedef __attribute__((ext_vector_type(4))) float f32x4;

__device__ __forceinline__ float gelu_f(float v){
  return 0.5f*v*(1.0f + erff(v*0.7071067811865476f));
}

__device__ __forceinline__ ushort f2bf(float f){
  union { float f; unsigned u; } v; v.f = f;
  unsigned u = v.u;
  u += 0x7fff + ((u >> 16) & 1);   // RNE
  return (ushort)(u >> 16);
}

// ---- prep: deform_w [64o][64c][9k] -> bt bf16 [9k][64o][64c]; expand_w [256][64] -> ewt[64][256]
__global__ void k_prep(const float* __restrict__ dw, const float* __restrict__ ew,
                       ushort* __restrict__ bt, float* __restrict__ ewt){
  int i = blockIdx.x*256 + threadIdx.x;
  if (i < 9*64*64){
    int k = i >> 12;
    int r = i & 4095;
    int o = r >> 6, c = r & 63;
    bt[i] = f2bf(dw[(o*64+c)*9 + k]);
  }
  int j = i - 9*64*64;
  if (j >= 0 && j < 64*256){
    int m = j >> 8, c = j & 255;
    ewt[j] = ew[c*64 + m];
  }
}

// ---- compress 1x1: feat NCHW -> x NHWC [b][p][64]
__global__ __launch_bounds__(256) void k_compress(const float* __restrict__ feat,
    const float* __restrict__ cw, const float* __restrict__ cb, float* __restrict__ xo){
  __shared__ float wl[256*64];           // wl[c*64+m] = cw[m*256+c]  (64KB)
  int t = threadIdx.x;
  for (int i=t;i<256*64;i+=256){ int c=i>>6, m=i&63; wl[i]=cw[m*256+c]; }
  __syncthreads();
  int b = blockIdx.y;
  int p = blockIdx.x*256 + t;
  const float* fp = feat + (size_t)b*CC*HW + p;
  float acc[64];
  #pragma unroll
  for (int m=0;m<64;m++) acc[m]=cb[m];
  #pragma unroll 2
  for (int c=0;c<256;c++){
    float f = fp[(size_t)c*HW];
    const float* w = &wl[c*64];
    #pragma unroll
    for (int m=0;m<64;m+=4){
      float4 w4 = *(const float4*)(w+m);
      acc[m]+=f*w4.x; acc[m+1]+=f*w4.y; acc[m+2]+=f*w4.z; acc[m+3]+=f*w4.w;
    }
  }
  float* xp = xo + ((size_t)b*HW + p)*64;
  #pragma unroll
  for (int m=0;m<64;m+=4) *(float4*)(xp+m)=make_float4(acc[m],acc[m+1],acc[m+2],acc[m+3]);
}

// ---- off1: wind [b][2][H][W] -> h NHWC [b][p][32], conv3x3 pad1 + gelu
__global__ __launch_bounds__(256) void k_off1(const float* __restrict__ wind,
    const float* __restrict__ w1, const float* __restrict__ b1, float* __restrict__ ho){
  __shared__ float wl[576];              // [o][c][k] = [32][2][9]
  int t=threadIdx.x;
  for (int i=t;i<576;i+=256) wl[i]=w1[i];
  __syncthreads();
  int b=blockIdx.y; int p=blockIdx.x*256+t;
  int y=p>>7, x=p&127;
  float tap[18];
  #pragma unroll
  for (int c=0;c<2;c++){
    #pragma unroll
    for (int ki=0;ki<3;ki++){
      #pragma unroll
      for (int kj=0;kj<3;kj++){
        int yy=y+ki-1, xx=x+kj-1;
        float v=0.f;
        if ((unsigned)yy<128u && (unsigned)xx<128u)
          v = wind[((size_t)b*2+c)*HW + (yy<<7)+xx];
        tap[c*9+ki*3+kj]=v;
      }
    }
  }
  float outv[32];
  #pragma unroll
  for (int o=0;o<32;o++){
    float a=b1[o];
    #pragma unroll
    for (int i=0;i<18;i++) a += tap[i]*wl[o*18+i];
    outv[o]=gelu_f(a);
  }
  float* hp = ho + ((size_t)b*HW+p)*32;
  #pragma unroll
  for (int o=0;o<32;o+=4) *(float4*)(hp+o)=make_float4(outv[o],outv[o+1],outv[o+2],outv[o+3]);
}

// ---- off2: h NHWC [b][p][32] -> offsets NHWC [b][p][18], conv3x3 pad1
__global__ __launch_bounds__(256) void k_off2(const float* __restrict__ h,
    const float* __restrict__ w2, const float* __restrict__ b2, float* __restrict__ oo){
  __shared__ float wl[9*18*32];          // wl[(k*18+o)*32+c] (20.7KB)
  int t=threadIdx.x;
  for (int i=t;i<5184;i+=256){
    int k=i/576; int r=i-k*576; int o=r>>5; int c=r&31;
    wl[i] = w2[(o*32+c)*9+k];
  }
  __syncthreads();
  int b=blockIdx.y; int p=blockIdx.x*256+t;
  int y=p>>7, x=p&127;
  float acc[18];
  #pragma unroll
  for (int o=0;o<18;o++) acc[o]=b2[o];
  for (int ki=0;ki<3;ki++){
    for (int kj=0;kj<3;kj++){
      int k = ki*3+kj;
      int yy=y+ki-1, xx=x+kj-1;
      float4 hv[8];
      if ((unsigned)yy<128u && (unsigned)xx<128u){
        const float* hp = h + ((size_t)b*HW + (yy<<7)+xx)*32;
        #pragma unroll
        for (int q=0;q<8;q++) hv[q]=*(const float4*)(hp+q*4);
      } else {
        #pragma unroll
        for (int q=0;q<8;q++) hv[q]=make_float4(0.f,0.f,0.f,0.f);
      }
      const float* wk = &wl[k*576];
      #pragma unroll
      for (int o=0;o<18;o++){
        float a=acc[o];
        #pragma unroll
        for (int q=0;q<8;q++){
          float4 w4 = *(const float4*)(wk + o*32 + q*4);
          a += hv[q].x*w4.x + hv[q].y*w4.y + hv[q].z*w4.z + hv[q].w*w4.w;
        }
        acc[o]=a;
      }
    }
  }
  float* op = oo + ((size_t)b*HW+p)*18;
  #pragma unroll
  for (int o=0;o<18;o+=2) *(float2*)(op+o)=make_float2(acc[o],acc[o+1]);
}

// ---- deform conv via MFMA bf16:
// x NHWC fp32, offsets NHWC, bt bf16 [9][64 o][64 c] -> y NHWC [b][p][64]
// Block: one image row (128 px), 4 waves. Per tap: gather+pack A tile
// [128px][64c] bf16 into xor-swizzled LDS, then each wave does 8 px-tiles x
// 2 ksteps of mfma_f32_16x16x32_bf16 against B frags from global (L2-hot).
__global__ __launch_bounds__(256) void k_deform(
    const float* __restrict__ x, const float* __restrict__ off,
    const ushort* __restrict__ bt, const float* __restrict__ db,
    float* __restrict__ yo){
  __shared__ ushort A[128*64];           // 16 KB; row=px (128B), 16B chunks xor-swizzled by px&7
  int t = threadIdx.x;
  int r = blockIdx.x;                    // image row
  int b = blockIdx.y;
  int p0 = r*128;
  int px_l = t & 127, half = t >> 7;     // gather role: pixel + channel-half
  int p = p0 + px_l;
  const float* xb = x + (size_t)b*HW*64;
  const float* offp = off + ((size_t)b*HW + p)*18;
  float2 offv[9];
  #pragma unroll
  for (int k=0;k<9;k++) offv[k] = *(const float2*)(offp + 2*k);

  int lane = t & 63, w = t >> 6;         // MFMA role
  int qd = lane >> 4, ln = lane & 15;
  int n = (w<<4) + ln;                   // output channel for this lane
  f32x4 acc[8];
  #pragma unroll
  for (int pt=0;pt<8;pt++) acc[pt] = (f32x4){0.f,0.f,0.f,0.f};

  for (int k=0;k<9;k++){
    // B fragments for this tap (global; 73KB table stays in L2)
    const ushort* btk = bt + (((k<<6) + n)<<6) + (qd<<3);
    bf16x8 bf0 = *(const bf16x8*)btk;
    bf16x8 bf1 = *(const bf16x8*)(btk + 32);

    // bilinear gather 32 channels for (px_l, half) into registers
    int ki = k/3, kj = k - ki*3;
    float py  = offv[k].x + (float)(r + ki - 1);
    float pxf = offv[k].y + (float)(px_l + kj - 1);
    float y0f = floorf(py), x0f = floorf(pxf);
    float fy = py - y0f, fx = pxf - x0f;
    int y0 = (int)y0f, x0 = (int)x0f;
    float w00=(1.f-fy)*(1.f-fx), w01=(1.f-fy)*fx, w10=fy*(1.f-fx), w11=fy*fx;
    bool v0=((unsigned)y0<128u), v1=((unsigned)(y0+1)<128u);
    bool u0=((unsigned)x0<128u), u1=((unsigned)(x0+1)<128u);
    bool b00=v0&&u0, b01=v0&&u1, b10=v1&&u0, b11=v1&&u1;
    long base = (long)y0*8192 + (long)x0*64 + (half<<5);
    const float4 z4 = make_float4(0.f,0.f,0.f,0.f);
    int4 pk[4];
    #pragma unroll
    for (int cc=0;cc<4;cc++){
      unsigned pw[4];
      #pragma unroll
      for (int h=0;h<2;h++){
        int c4 = (cc*2+h)*4;
        float4 v00 = b00 ? *(const float4*)(xb+base+c4)        : z4;
        float4 v01 = b01 ? *(const float4*)(xb+base+64+c4)     : z4;
        float4 v10 = b10 ? *(const float4*)(xb+base+8192+c4)   : z4;
        float4 v11 = b11 ? *(const float4*)(xb+base+8256+c4)   : z4;
        float4 s;
        s.x = v00.x*w00 + v01.x*w01 + v10.x*w10 + v11.x*w11;
        s.y = v00.y*w00 + v01.y*w01 + v10.y*w10 + v11.y*w11;
        s.z = v00.z*w00 + v01.z*w01 + v10.z*w10 + v11.z*w11;
        s.w = v00.w*w00 + v01.w*w01 + v10.w*w10 + v11.w*w11;
        pw[h*2]   = (unsigned)f2bf(s.x) | ((unsigned)f2bf(s.y)<<16);
        pw[h*2+1] = (unsigned)f2bf(s.z) | ((unsigned)f2bf(s.w)<<16);
      }
      pk[cc] = make_int4((int)pw[0],(int)pw[1],(int)pw[2],(int)pw[3]);
    }
    __syncthreads();                     // previous tap's MFMA reads done
    #pragma unroll
    for (int cc=0;cc<4;cc++){
      int swz = ((half<<2)+cc) ^ (px_l & 7);
      *(int4*)((int*)(A + px_l*64 + swz*8)) = pk[cc];
    }
    __syncthreads();                     // A tile ready

    #pragma unroll
    for (int pt=0;pt<8;pt++){
      int m = (pt<<4) + ln;              // pixel row in tile
      int ch0 = qd ^ (m&7);              // kstep0 chunk (chunk=qd)
      int ch1 = (4+qd) ^ (m&7);          // kstep1 chunk (chunk=4+qd)
      bf16x8 a0 = *(bf16x8*)(A + (m<<6) + (ch0<<3));
      acc[pt] = __builtin_amdgcn_mfma_f32_16x16x32_bf16(a0, bf0, acc[pt], 0,0,0);
      bf16x8 a1 = *(bf16x8*)(A + (m<<6) + (ch1<<3));
      acc[pt] = __builtin_amdgcn_mfma_f32_16x16x32_bf16(a1, bf1, acc[pt], 0,0,0);
    }
  }
  // epilogue: C/D layout col=lane&15 (=output ch offset), row=(lane>>4)*4+reg (=px in tile)
  float bias = db[n];
  float* yb2 = yo + ((size_t)b*HW + p0)*64 + n;
  #pragma unroll
  for (int pt=0;pt<8;pt++){
    #pragma unroll
    for (int rg=0;rg<4;rg++){
      int pxr = (pt<<4) + (qd<<2) + rg;
      yb2[(size_t)pxr*64] = acc[pt][rg] + bias;
    }
  }
}

// ---- stats: ybar[b][64] = sum_p y, Y2[b][64][64] = sum_p y y^T (atomic partials)
__global__ __launch_bounds__(256) void k_stats(const float* __restrict__ y,
    float* __restrict__ Y2, float* __restrict__ ybar){
  __shared__ float yt[128*64];           // 32KB
  int t=threadIdx.x; int b=blockIdx.y;
  const float* yp = y + ((size_t)b*HW + blockIdx.x*128)*64;
  for (int i=t*4;i<8192;i+=1024) *(float4*)&yt[i]=*(const float4*)(yp+i);
  __syncthreads();
  int i = t&63, jb = t>>6;
  float acc[16];
  #pragma unroll
  for (int j=0;j<16;j++) acc[j]=0.f;
  for (int p=0;p<128;p++){
    float yi = yt[(p<<6)+i];
    const float* yj = &yt[(p<<6)+(jb<<4)];
    #pragma unroll
    for (int q=0;q<4;q++){
      float4 v=*(const float4*)(yj+q*4);
      acc[q*4]+=yi*v.x; acc[q*4+1]+=yi*v.y; acc[q*4+2]+=yi*v.z; acc[q*4+3]+=yi*v.w;
    }
  }
  float* Y2b = Y2 + ((size_t)b<<12) + (i<<6) + (jb<<4);
  #pragma unroll
  for (int j=0;j<16;j++) atomicAdd(Y2b+j, acc[j]);
  if (t<64){
    float s=0.f;
    for (int p=0;p<128;p++) s+=yt[(p<<6)+t];
    atomicAdd(ybar+(b<<6)+t, s);
  }
}

// ---- analytic GN stats: per (b,g): mu, rstd of z = expand(y) over 64ch x HW
__global__ __launch_bounds__(256) void k_gn(const float* __restrict__ Y2,
    const float* __restrict__ ybar, const float* __restrict__ ew,
    const float* __restrict__ eb, float* __restrict__ stats){
  __shared__ float wsm[64*65];
  __shared__ float red[512];
  int t=threadIdx.x;
  int bg=blockIdx.x, b=bg>>2, g=bg&3;
  for (int i=t;i<4096;i+=256){
    int c=i>>6, m=i&63;
    wsm[c*65+m] = ew[(((size_t)g<<6)+c)*64 + m];
  }
  __syncthreads();
  int c = t&63, qm = t>>6;
  const float* wv = &wsm[c*65];
  const float* Y2b = Y2 + ((size_t)b<<12);
  const float* yb = ybar + (b<<6);
  float q=0.f, sbp=0.f;
  for (int m=qm*16; m<qm*16+16; m++){
    const float* row = Y2b + (m<<6);
    float ym=0.f;
    for (int nn=0;nn<64;nn+=4){
      float4 r4=*(const float4*)(row+nn);
      ym += r4.x*wv[nn] + r4.y*wv[nn+1] + r4.z*wv[nn+2] + r4.w*wv[nn+3];
    }
    q += ym*wv[m];
    sbp += wv[m]*yb[m];
  }
  float bias = eb[(g<<6)+c];
  float pz  = sbp + (qm==0 ? 16384.f*bias : 0.f);
  float pz2 = q + 2.f*bias*sbp + (qm==0 ? 16384.f*bias*bias : 0.f);
  red[t]=pz; red[256+t]=pz2;
  __syncthreads();
  for (int s=128;s>0;s>>=1){
    if (t<s){ red[t]+=red[t+s]; red[256+t]+=red[256+t+s]; }
    __syncthreads();
  }
  if (t==0){
    const float N=64.f*16384.f;
    float mu = red[0]/N;
    float var = red[256]/N - mu*mu;
    stats[bg*2]=mu; stats[bg*2+1]=rsqrtf(var+1e-5f);
  }
}

// ---- final: recompute z = expand(y), GN apply, gelu, + features -> out NCHW
__global__ __launch_bounds__(256) void k_final(const float* __restrict__ y,
    const float* __restrict__ ewt, const float* __restrict__ eb,
    const float* __restrict__ stats, const float* __restrict__ gamma,
    const float* __restrict__ beta, const float* __restrict__ feat,
    float* __restrict__ out){
  __shared__ float yt[128*65];           // y tile [px][m], pad 65 (33.3KB)
  __shared__ float wl[64*68];            // W^T block [m][c_local], pad 68 (17.4KB)
  int t=threadIdx.x; int b=blockIdx.y; int g=blockIdx.z;
  int p0 = blockIdx.x*128;
  const float* yp = y + ((size_t)b*HW+p0)*64;
  for (int i=t*4;i<8192;i+=1024){
    float4 v=*(const float4*)(yp+i);
    int l=i>>6, m=i&63;
    float* dst=&yt[l*65+m];
    dst[0]=v.x; dst[1]=v.y; dst[2]=v.z; dst[3]=v.w;
  }
  for (int i=t;i<4096;i+=256){
    int m=i>>6, cl=i&63;
    wl[m*68+cl] = ewt[(m<<8) + (g<<6) + cl];
  }
  __syncthreads();
  int l = t & 127, ch = (t>>7)<<5;       // c_local base: 0 or 32
  int p = p0 + l;
  int cg0 = (g<<6) + ch;
  float acc[32];
  #pragma unroll
  for (int j=0;j<32;j++) acc[j]=eb[cg0+j];
  for (int m=0;m<64;m++){
    float yv = yt[l*65+m];
    const float* wm = &wl[m*68+ch];
    #pragma unroll
    for (int q=0;q<8;q++){
      float4 w4=*(const float4*)(wm+q*4);
      acc[q*4]+=yv*w4.x; acc[q*4+1]+=yv*w4.y; acc[q*4+2]+=yv*w4.z; acc[q*4+3]+=yv*w4.w;
    }
  }
  float mu = stats[(((b<<2)+g)<<1)], rstd = stats[(((b<<2)+g)<<1)+1];
  #pragma unroll
  for (int j=0;j<32;j++){
    int cg = cg0 + j;
    float zn = (acc[j]-mu)*rstd;
    float val = zn*gamma[cg] + beta[cg];
    size_t idx = ((size_t)b*CC + cg)*HW + p;
    out[idx] = feat[idx] + gelu_f(val);
  }
}

extern "C" void kernel_launch(void* const* d_in, const int* in_sizes, int n_in,
                              void* d_out, int out_size, void* d_ws, size_t ws_size,
                              hipStream_t stream){
  const float* feat = (const float*)d_in[0];
  const float* wind = (const float*)d_in[1];
  const float* cw   = (const float*)d_in[2];
  const float* cb   = (const float*)d_in[3];
  const float* w1   = (const float*)d_in[4];
  const float* b1   = (const float*)d_in[5];
  const float* w2   = (const float*)d_in[6];
  const float* b2   = (const float*)d_in[7];
  const float* dw   = (const float*)d_in[8];
  const float* db   = (const float*)d_in[9];
  const float* ew   = (const float*)d_in[10];
  const float* ebias= (const float*)d_in[11];
  const float* gg   = (const float*)d_in[12];
  const float* gb   = (const float*)d_in[13];
  float* ws = (float*)d_ws;
  // ws layout (floats)
  float* x_nhwc   = ws;                    // 8*16384*64  = 8388608
  float* y_nhwc   = ws + 8388608;          // 8388608
  float* h_nhwc   = ws + 16777216;         // 8*16384*32 = 4194304
  float* off_nhwc = ws + 20971520;         // 8*16384*18 = 2359296
  ushort* bt      = (ushort*)(ws + 23330816); // 9*64*64 bf16 = 18432 floats
  float* ewt      = ws + 23367680;         // 64*256  = 16384
  float* Y2       = ws + 23384064;         // 8*4096  = 32768
  float* ybar     = ws + 23416832;         // 8*64    = 512
  float* stats    = ws + 23417344;         // 8*4*2   = 64
  hipMemsetAsync(Y2, 0, (32768+512)*sizeof(float), stream);
  k_prep<<<208,256,0,stream>>>(dw, ew, bt, ewt);
  k_compress<<<dim3(64,8),256,0,stream>>>(feat, cw, cb, x_nhwc);
  k_off1<<<dim3(64,8),256,0,stream>>>(wind, w1, b1, h_nhwc);
  k_off2<<<dim3(64,8),256,0,stream>>>(h_nhwc, w2, b2, off_nhwc);
  k_deform<<<dim3(128,8),256,0,stream>>>(x_nhwc, off_nhwc, bt, db, y_nhwc);
  k_stats<<<dim3(128,8),256,0,stream>>>(y_nhwc, Y2, ybar);
  k_gn<<<32,256,0,stream>>>(Y2, ybar, ew, ebias, stats);
  k_final<<<dim3(128,8,4),256,0,stream>>>(y_nhwc, ewt, ebias, stats, gg, gb, feat, (float*)d_out);
}

// Round 3
// 719.038 us; speedup vs baseline: 2.0702x; 1.9057x over previous
//
#include <hip/hip_runtime.h>
#include <math.h>

// WindAdvectionBlock: B=8, C=256, H=W=128, mid=64
// compress(1x1,MFMA) -> off1+gelu -> off2 -> deform(MFMA, coalesced gather,
// XCD-swizzled) -> [analytic GN stats] -> final(MFMA expand+GN+gelu+residual)

#define BB 8
#define CC 256
#define HW 16384
#define MID 64

typedef __attribute__((ext_vector_type(8))) short bf16x8;
typedef __attribute__((ext_vector_type(4))) float f32x4;

__device__ __forceinline__ float gelu_f(float v){
  return 0.5f*v*(1.0f + erff(v*0.7071067811865476f));
}
__device__ __forceinline__ unsigned f2bf(float f){
  union { float f; unsigned u; } v; v.f = f;
  unsigned u = v.u;
  u += 0x7fff + ((u >> 16) & 1);   // RNE
  return (u >> 16);
}

// ---- prep: bt bf16 [9][64o][64c] from dw [64o][64c][9]; cwb bf16 [64o][256c];
//            ewb bf16 [256o][64c]
__global__ void k_prep(const float* __restrict__ dw, const float* __restrict__ cw,
                       const float* __restrict__ ew, ushort* __restrict__ bt,
                       ushort* __restrict__ cwb, ushort* __restrict__ ewb){
  int i = blockIdx.x*256 + threadIdx.x;
  if (i < 36864){
    int k = i >> 12, r = i & 4095;
    int o = r >> 6, c = r & 63;
    bt[i] = (ushort)f2bf(dw[(o*64+c)*9 + k]);
  }
  int j = i - 36864;
  if (j >= 0 && j < 16384) cwb[j] = (ushort)f2bf(cw[j]);
  int l = i - 53248;
  if (l >= 0 && l < 16384) ewb[l] = (ushort)f2bf(ew[l]);
}

// ---- compress 1x1 via MFMA: feat NCHW -> x NHWC [b][p][64]
// block = 128 px; K-loop 4 tiles of 64 ch; A staged via register transpose.
__global__ __launch_bounds__(256) void k_compress(const float* __restrict__ feat,
    const ushort* __restrict__ cwb, const float* __restrict__ cb, float* __restrict__ xo){
  __shared__ ushort A[128*64];           // 16 KB, [px][64c] bf16, 16B chunks xor px&7
  int t = threadIdx.x;
  int b = blockIdx.y, p0 = blockIdx.x*128;
  int lane = t & 63, w = t >> 6, ln = lane & 15, qd = lane >> 4;
  int n = (w<<4) + ln;                   // out channel
  int cg = t >> 4, pxg = t & 15;         // staging: 4-ch group, 8-px group
  f32x4 acc[8];
  #pragma unroll
  for (int pt=0;pt<8;pt++) acc[pt] = (f32x4){0.f,0.f,0.f,0.f};
  for (int kt=0;kt<4;kt++){
    // load 4 channels x 8 px into regs
    const float* fb = feat + ((size_t)(b*CC + kt*64 + cg*4))*HW + p0 + pxg*8;
    float v[4][8];
    #pragma unroll
    for (int i=0;i<4;i++){
      *(float4*)&v[i][0] = *(const float4*)(fb + (size_t)i*HW);
      *(float4*)&v[i][4] = *(const float4*)(fb + (size_t)i*HW + 4);
    }
    __syncthreads();                     // prev tile's readers done
    #pragma unroll
    for (int j=0;j<8;j++){
      int px = pxg*8 + j;
      unsigned lo = f2bf(v[0][j]) | (f2bf(v[1][j])<<16);
      unsigned hi = f2bf(v[2][j]) | (f2bf(v[3][j])<<16);
      int chunk = (cg>>1) ^ (px&7);
      *(uint2*)((char*)A + px*128 + chunk*16 + (cg&1)*8) = make_uint2(lo,hi);
    }
    __syncthreads();
    const ushort* wb = cwb + (size_t)n*256 + kt*64 + (qd<<3);
    bf16x8 b0 = *(const bf16x8*)wb;
    bf16x8 b1 = *(const bf16x8*)(wb + 32);
    #pragma unroll
    for (int pt=0;pt<8;pt++){
      int m = (pt<<4) + ln;
      int ch0 = qd ^ (m&7), ch1 = (4+qd) ^ (m&7);
      bf16x8 a0 = *(bf16x8*)(A + (m<<6) + (ch0<<3));
      acc[pt] = __builtin_amdgcn_mfma_f32_16x16x32_bf16(a0, b0, acc[pt], 0,0,0);
      bf16x8 a1 = *(bf16x8*)(A + (m<<6) + (ch1<<3));
      acc[pt] = __builtin_amdgcn_mfma_f32_16x16x32_bf16(a1, b1, acc[pt], 0,0,0);
    }
  }
  float bias = cb[n];
  float* xp = xo + ((size_t)(b*HW + p0))*64 + n;
  #pragma unroll
  for (int pt=0;pt<8;pt++){
    #pragma unroll
    for (int rg=0;rg<4;rg++){
      int px = (pt<<4) + (qd<<2) + rg;
      xp[(size_t)px*64] = acc[pt][rg] + bias;
    }
  }
}

// ---- off1: wind [b][2][H][W] -> h NHWC [b][p][32], conv3x3 pad1 + gelu
__global__ __launch_bounds__(256) void k_off1(const float* __restrict__ wind,
    const float* __restrict__ w1, const float* __restrict__ b1, float* __restrict__ ho){
  __shared__ float wl[576];
  int t=threadIdx.x;
  for (int i=t;i<576;i+=256) wl[i]=w1[i];
  __syncthreads();
  int b=blockIdx.y; int p=blockIdx.x*256+t;
  int y=p>>7, x=p&127;
  float tap[18];
  #pragma unroll
  for (int c=0;c<2;c++){
    #pragma unroll
    for (int ki=0;ki<3;ki++){
      #pragma unroll
      for (int kj=0;kj<3;kj++){
        int yy=y+ki-1, xx=x+kj-1;
        float v=0.f;
        if ((unsigned)yy<128u && (unsigned)xx<128u)
          v = wind[((size_t)b*2+c)*HW + (yy<<7)+xx];
        tap[c*9+ki*3+kj]=v;
      }
    }
  }
  float outv[32];
  #pragma unroll
  for (int o=0;o<32;o++){
    float a=b1[o];
    #pragma unroll
    for (int i=0;i<18;i++) a += tap[i]*wl[o*18+i];
    outv[o]=gelu_f(a);
  }
  float* hp = ho + ((size_t)(b*HW+p))*32;
  #pragma unroll
  for (int o=0;o<32;o+=4) *(float4*)(hp+o)=make_float4(outv[o],outv[o+1],outv[o+2],outv[o+3]);
}

// ---- off2: h NHWC [b][p][32] -> offsets NHWC [b][p][18], conv3x3 pad1
__global__ __launch_bounds__(256) void k_off2(const float* __restrict__ h,
    const float* __restrict__ w2, const float* __restrict__ b2, float* __restrict__ oo){
  __shared__ float wl[9*18*32];
  int t=threadIdx.x;
  for (int i=t;i<5184;i+=256){
    int k=i/576; int r=i-k*576; int o=r>>5; int c=r&31;
    wl[i] = w2[(o*32+c)*9+k];
  }
  __syncthreads();
  int b=blockIdx.y; int p=blockIdx.x*256+t;
  int y=p>>7, x=p&127;
  float acc[18];
  #pragma unroll
  for (int o=0;o<18;o++) acc[o]=b2[o];
  for (int ki=0;ki<3;ki++){
    for (int kj=0;kj<3;kj++){
      int k = ki*3+kj;
      int yy=y+ki-1, xx=x+kj-1;
      float4 hv[8];
      if ((unsigned)yy<128u && (unsigned)xx<128u){
        const float* hp = h + ((size_t)(b*HW) + (yy<<7)+xx)*32;
        #pragma unroll
        for (int q=0;q<8;q++) hv[q]=*(const float4*)(hp+q*4);
      } else {
        #pragma unroll
        for (int q=0;q<8;q++) hv[q]=make_float4(0.f,0.f,0.f,0.f);
      }
      const float* wk = &wl[k*576];
      #pragma unroll
      for (int o=0;o<18;o++){
        float a=acc[o];
        #pragma unroll
        for (int q=0;q<8;q++){
          float4 w4 = *(const float4*)(wk + o*32 + q*4);
          a += hv[q].x*w4.x + hv[q].y*w4.y + hv[q].z*w4.z + hv[q].w*w4.w;
        }
        acc[o]=a;
      }
    }
  }
  float* op = oo + ((size_t)(b*HW+p))*18;
  #pragma unroll
  for (int o=0;o<18;o+=2) *(float2*)(op+o)=make_float2(acc[o],acc[o+1]);
}

// ---- deform conv MFMA, coalesced gather.
// Grid 1024 linear: b = blk&7 (XCD locality), r = blk>>3.
// Gather role: lane = p_sub(qd)*? -> pixel p = w*32 + pp*4 + qd, chunk c4 = ln.
// Each load instr: 4 adjacent pixel rows x 256B contiguous.
__global__ __launch_bounds__(256) void k_deform(
    const float* __restrict__ x, const float* __restrict__ off,
    const ushort* __restrict__ bt, const float* __restrict__ db,
    float* __restrict__ yo){
  __shared__ ushort A[128*64];           // 16 KB
  __shared__ float offs[128*18];         // 9 KB
  int t = threadIdx.x;
  int blk = blockIdx.x;
  int b = blk & 7, r = blk >> 3;
  int p0 = r*128;
  const float* offg = off + ((size_t)(b*HW + p0))*18;
  for (int i=t;i<576;i+=256)
    *(float4*)(offs + i*4) = *(const float4*)(offg + i*4);
  __syncthreads();
  int lane = t & 63, w = t >> 6, ln = lane & 15, qd = lane >> 4;
  int n = (w<<4) + ln;
  const float* xb = x + (size_t)b*HW*64;
  f32x4 acc[8];
  #pragma unroll
  for (int pt=0;pt<8;pt++) acc[pt] = (f32x4){0.f,0.f,0.f,0.f};

  for (int k=0;k<9;k++){
    int ki = k/3, kj = k - ki*3;
    const ushort* btk = bt + (size_t)(((k<<6) + n)<<6) + (qd<<3);
    bf16x8 bf0 = *(const bf16x8*)btk;
    bf16x8 bf1 = *(const bf16x8*)(btk + 32);
    __syncthreads();                     // prev tap's MFMA reads done
    #pragma unroll
    for (int pp=0;pp<8;pp++){
      int p = (w<<5) + (pp<<2) + qd;     // pixel (x-coord) 0..127
      float2 dd = *(const float2*)(offs + p*18 + 2*k);
      float py  = dd.x + (float)(r + ki - 1);
      float pxs = dd.y + (float)(p + kj - 1);
      float y0f = floorf(py), x0f = floorf(pxs);
      float fy = py - y0f, fx = pxs - x0f;
      int y0 = (int)y0f, x0 = (int)x0f;
      float w00=(1.f-fy)*(1.f-fx), w01=(1.f-fy)*fx, w10=fy*(1.f-fx), w11=fy*fx;
      bool v0=((unsigned)y0<128u), v1=((unsigned)(y0+1)<128u);
      bool u0=((unsigned)x0<128u), u1=((unsigned)(x0+1)<128u);
      w00 = (v0&&u0)? w00 : 0.f;  w01 = (v0&&u1)? w01 : 0.f;
      w10 = (v1&&u0)? w10 : 0.f;  w11 = (v1&&u1)? w11 : 0.f;
      int y0c = min(max(y0,0),127), y1c = min(max(y0+1,0),127);
      int x0c = min(max(x0,0),127), x1c = min(max(x0+1,0),127);
      int cofs = (ln<<2);
      const float4* r00 = (const float4*)(xb + (size_t)y0c*8192 + x0c*64 + cofs);
      const float4* r01 = (const float4*)(xb + (size_t)y0c*8192 + x1c*64 + cofs);
      const float4* r10 = (const float4*)(xb + (size_t)y1c*8192 + x0c*64 + cofs);
      const float4* r11 = (const float4*)(xb + (size_t)y1c*8192 + x1c*64 + cofs);
      float4 a00=*r00, a01=*r01, a10=*r10, a11=*r11;
      float4 s;
      s.x = a00.x*w00 + a01.x*w01 + a10.x*w10 + a11.x*w11;
      s.y = a00.y*w00 + a01.y*w01 + a10.y*w10 + a11.y*w11;
      s.z = a00.z*w00 + a01.z*w01 + a10.z*w10 + a11.z*w11;
      s.w = a00.w*w00 + a01.w*w01 + a10.w*w10 + a11.w*w11;
      unsigned lo = f2bf(s.x) | (f2bf(s.y)<<16);
      unsigned hi = f2bf(s.z) | (f2bf(s.w)<<16);
      int chunk = (ln>>1) ^ (p&7);
      *(uint2*)((char*)A + p*128 + chunk*16 + (ln&1)*8) = make_uint2(lo,hi);
    }
    __syncthreads();                     // A tile ready
    #pragma unroll
    for (int pt=0;pt<8;pt++){
      int m = (pt<<4) + ln;
      int ch0 = qd ^ (m&7), ch1 = (4+qd) ^ (m&7);
      bf16x8 a0 = *(bf16x8*)(A + (m<<6) + (ch0<<3));
      acc[pt] = __builtin_amdgcn_mfma_f32_16x16x32_bf16(a0, bf0, acc[pt], 0,0,0);
      bf16x8 a1 = *(bf16x8*)(A + (m<<6) + (ch1<<3));
      acc[pt] = __builtin_amdgcn_mfma_f32_16x16x32_bf16(a1, bf1, acc[pt], 0,0,0);
    }
  }
  float bias = db[n];
  float* yp = yo + ((size_t)(b*HW + p0))*64 + n;
  #pragma unroll
  for (int pt=0;pt<8;pt++){
    #pragma unroll
    for (int rg=0;rg<4;rg++){
      int px = (pt<<4) + (qd<<2) + rg;
      yp[(size_t)px*64] = acc[pt][rg] + bias;
    }
  }
}

// ---- stats: ybar[b][64] = sum_p y, Y2[b][64][64] = sum_p y y^T (atomic partials)
__global__ __launch_bounds__(256) void k_stats(const float* __restrict__ y,
    float* __restrict__ Y2, float* __restrict__ ybar){
  __shared__ float yt[128*64];
  int t=threadIdx.x; int b=blockIdx.y;
  const float* yp = y + ((size_t)(b*HW) + blockIdx.x*128)*64;
  for (int i=t*4;i<8192;i+=1024) *(float4*)&yt[i]=*(const float4*)(yp+i);
  __syncthreads();
  int i = t&63, jb = t>>6;
  float acc[16];
  #pragma unroll
  for (int j=0;j<16;j++) acc[j]=0.f;
  for (int p=0;p<128;p++){
    float yi = yt[(p<<6)+i];
    const float* yj = &yt[(p<<6)+(jb<<4)];
    #pragma unroll
    for (int q=0;q<4;q++){
      float4 v=*(const float4*)(yj+q*4);
      acc[q*4]+=yi*v.x; acc[q*4+1]+=yi*v.y; acc[q*4+2]+=yi*v.z; acc[q*4+3]+=yi*v.w;
    }
  }
  float* Y2b = Y2 + ((size_t)b<<12) + (i<<6) + (jb<<4);
  #pragma unroll
  for (int j=0;j<16;j++) atomicAdd(Y2b+j, acc[j]);
  if (t<64){
    float s=0.f;
    for (int p=0;p<128;p++) s+=yt[(p<<6)+t];
    atomicAdd(ybar+(b<<6)+t, s);
  }
}

// ---- analytic GN stats per (b,g): mu, rstd of z = expand(y)
__global__ __launch_bounds__(256) void k_gn(const float* __restrict__ Y2,
    const float* __restrict__ ybar, const float* __restrict__ ew,
    const float* __restrict__ eb, float* __restrict__ stats){
  __shared__ float wsm[64*65];
  __shared__ float red[512];
  int t=threadIdx.x;
  int bg=blockIdx.x, b=bg>>2, g=bg&3;
  for (int i=t;i<4096;i+=256){
    int c=i>>6, m=i&63;
    wsm[c*65+m] = ew[(((size_t)g<<6)+c)*64 + m];
  }
  __syncthreads();
  int c = t&63, qm = t>>6;
  const float* wv = &wsm[c*65];
  const float* Y2b = Y2 + ((size_t)b<<12);
  const float* yb = ybar + (b<<6);
  float q=0.f, sbp=0.f;
  for (int m=qm*16; m<qm*16+16; m++){
    const float* row = Y2b + (m<<6);
    float ym=0.f;
    for (int nn=0;nn<64;nn+=4){
      float4 r4=*(const float4*)(row+nn);
      ym += r4.x*wv[nn] + r4.y*wv[nn+1] + r4.z*wv[nn+2] + r4.w*wv[nn+3];
    }
    q += ym*wv[m];
    sbp += wv[m]*yb[m];
  }
  float bias = eb[(g<<6)+c];
  float pz  = sbp + (qm==0 ? 16384.f*bias : 0.f);
  float pz2 = q + 2.f*bias*sbp + (qm==0 ? 16384.f*bias*bias : 0.f);
  red[t]=pz; red[256+t]=pz2;
  __syncthreads();
  for (int s=128;s>0;s>>=1){
    if (t<s){ red[t]+=red[t+s]; red[256+t]+=red[256+t+s]; }
    __syncthreads();
  }
  if (t==0){
    const float N=64.f*16384.f;
    float mu = red[0]/N;
    float var = red[256]/N - mu*mu;
    stats[bg*2]=mu; stats[bg*2+1]=rsqrtf(var+1e-5f);
  }
}

// ---- final MFMA: z = expand(y) (bf16 MFMA), GN apply + gelu + residual -> NCHW
// block = 128 px, wave w owns out-group g=w (64 ch = GN group).
__global__ __launch_bounds__(256) void k_final(const float* __restrict__ y,
    const ushort* __restrict__ ewb, const float* __restrict__ eb,
    const float* __restrict__ stats, const float* __restrict__ gamma,
    const float* __restrict__ beta, const float* __restrict__ feat,
    float* __restrict__ out){
  __shared__ ushort A[128*64];           // 16 KB bf16 y-tile
  __shared__ float T[64*132];            // 33 KB transpose buffer (pad 132)
  int t = threadIdx.x;
  int b = blockIdx.y, p0 = blockIdx.x*128;
  int lane = t & 63, w = t >> 6, ln = lane & 15, qd = lane >> 4;
  // stage A: thread covers px = t>>1, channels (t&1)*32..+31
  {
    int px = t>>1, ch0 = (t&1)*32;
    const float* yp = y + ((size_t)(b*HW + p0 + px))*64 + ch0;
    #pragma unroll
    for (int q=0;q<4;q++){
      float4 va = *(const float4*)(yp + q*8);
      float4 vb = *(const float4*)(yp + q*8 + 4);
      unsigned u0 = f2bf(va.x)|(f2bf(va.y)<<16);
      unsigned u1 = f2bf(va.z)|(f2bf(va.w)<<16);
      unsigned u2 = f2bf(vb.x)|(f2bf(vb.y)<<16);
      unsigned u3 = f2bf(vb.z)|(f2bf(vb.w)<<16);
      int chunk16 = (ch0 + q*8) >> 3;
      int phys = chunk16 ^ (px&7);
      *(uint4*)((char*)A + px*128 + phys*16) = make_uint4(u0,u1,u2,u3);
    }
  }
  __syncthreads();
  float mu = stats[((b<<2)+w)*2], rstd = stats[((b<<2)+w)*2+1];
  const float* fb = feat + (size_t)b*CC*HW + p0;
  float* ob = out + (size_t)b*CC*HW + p0;
  for (int nt=0;nt<4;nt++){
    int nch = (w<<6) + (nt<<4) + ln;
    const ushort* wb = ewb + (size_t)nch*64 + (qd<<3);
    bf16x8 b0 = *(const bf16x8*)wb;
    bf16x8 b1 = *(const bf16x8*)(wb + 32);
    f32x4 acc[8];
    #pragma unroll
    for (int pt=0;pt<8;pt++) acc[pt] = (f32x4){0.f,0.f,0.f,0.f};
    #pragma unroll
    for (int pt=0;pt<8;pt++){
      int m = (pt<<4) + ln;
      int ch0 = qd ^ (m&7), ch1 = (4+qd) ^ (m&7);
      bf16x8 a0 = *(bf16x8*)(A + (m<<6) + (ch0<<3));
      acc[pt] = __builtin_amdgcn_mfma_f32_16x16x32_bf16(a0, b0, acc[pt], 0,0,0);
      bf16x8 a1 = *(bf16x8*)(A + (m<<6) + (ch1<<3));
      acc[pt] = __builtin_amdgcn_mfma_f32_16x16x32_bf16(a1, b1, acc[pt], 0,0,0);
    }
    float bias = eb[nch];
    #pragma unroll
    for (int pt=0;pt<8;pt++){
      float4 v = make_float4(acc[pt][0]+bias, acc[pt][1]+bias,
                             acc[pt][2]+bias, acc[pt][3]+bias);
      *(float4*)&T[((w<<4)+ln)*132 + (pt<<4) + (qd<<2)] = v;
    }
    // read back wave-private block: 16 out rows x 128 px
    int orow = (w<<4) + (lane>>2);
    int c = (w<<6) + (nt<<4) + (lane>>2);
    float ga = gamma[c], be = beta[c];
    const float* frow = fb + (size_t)c*HW;
    float* orow_p = ob + (size_t)c*HW;
    #pragma unroll
    for (int it=0; it<8; it++){
      int px = it*16 + (lane&3)*4;
      float4 z = *(float4*)&T[orow*132 + px];
      float4 f = *(const float4*)(frow + px);
      float4 o;
      o.x = f.x + gelu_f((z.x-mu)*rstd*ga + be);
      o.y = f.y + gelu_f((z.y-mu)*rstd*ga + be);
      o.z = f.z + gelu_f((z.z-mu)*rstd*ga + be);
      o.w = f.w + gelu_f((z.w-mu)*rstd*ga + be);
      *(float4*)(orow_p + px) = o;
    }
  }
}

extern "C" void kernel_launch(void* const* d_in, const int* in_sizes, int n_in,
                              void* d_out, int out_size, void* d_ws, size_t ws_size,
                              hipStream_t stream){
  const float* feat = (const float*)d_in[0];
  const float* wind = (const float*)d_in[1];
  const float* cw   = (const float*)d_in[2];
  const float* cb   = (const float*)d_in[3];
  const float* w1   = (const float*)d_in[4];
  const float* b1   = (const float*)d_in[5];
  const float* w2   = (const float*)d_in[6];
  const float* b2   = (const float*)d_in[7];
  const float* dw   = (const float*)d_in[8];
  const float* db   = (const float*)d_in[9];
  const float* ew   = (const float*)d_in[10];
  const float* ebias= (const float*)d_in[11];
  const float* gg   = (const float*)d_in[12];
  const float* gb   = (const float*)d_in[13];
  float* ws = (float*)d_ws;
  float* x_nhwc   = ws;                    // 8388608
  float* y_nhwc   = ws + 8388608;          // 8388608
  float* h_nhwc   = ws + 16777216;         // 4194304
  float* off_nhwc = ws + 20971520;         // 2359296
  ushort* bt      = (ushort*)(ws + 23330816); // 36864 ush = 18432 fl
  ushort* cwb     = (ushort*)(ws + 23349248); // 16384 ush = 8192 fl
  ushort* ewb     = (ushort*)(ws + 23357440); // 16384 ush = 8192 fl
  float* Y2       = ws + 23365632;         // 32768
  float* ybar     = ws + 23398400;         // 512
  float* stats    = ws + 23398912;         // 64
  hipMemsetAsync(Y2, 0, (32768+512)*sizeof(float), stream);
  k_prep<<<272,256,0,stream>>>(dw, cw, ew, bt, cwb, ewb);
  k_compress<<<dim3(128,8),256,0,stream>>>(feat, cwb, cb, x_nhwc);
  k_off1<<<dim3(64,8),256,0,stream>>>(wind, w1, b1, h_nhwc);
  k_off2<<<dim3(64,8),256,0,stream>>>(h_nhwc, w2, b2, off_nhwc);
  k_deform<<<1024,256,0,stream>>>(x_nhwc, off_nhwc, bt, db, y_nhwc);
  k_stats<<<dim3(128,8),256,0,stream>>>(y_nhwc, Y2, ybar);
  k_gn<<<32,256,0,stream>>>(Y2, ybar, ew, ebias, stats);
  k_final<<<dim3(128,8),256,0,stream>>>(y_nhwc, ewb, ebias, stats, gg, gb, feat, (float*)d_out);
}